// Round 6
// baseline (290.766 us; speedup 1.0000x reference)
//
#include <hip/hip_runtime.h>

typedef unsigned short u16;
typedef unsigned int   u32;
using bf16x8 = __attribute__((ext_vector_type(8))) __bf16;
using f32x4  = __attribute__((ext_vector_type(4))) float;
using u32x2  = __attribute__((ext_vector_type(2))) unsigned int;

__device__ __forceinline__ u16 f2b(float f){
  union { float f; u32 i; } v; v.f = f;
  u32 r = v.i + 0x7FFFu + ((v.i >> 16) & 1u);
  return (u16)(r >> 16);
}
__device__ __forceinline__ u32 pk_bf16_trunc(float a, float b){
  return __builtin_amdgcn_perm(__float_as_uint(b), __float_as_uint(a), 0x07060302u);
}

#define GLL(gp, lp) __builtin_amdgcn_global_load_lds( \
    (const __attribute__((address_space(1))) void*)(gp), \
    (__attribute__((address_space(3))) void*)(lp), 16, 0, 0)

// ---------------------------------------------------------------- fp32 -> bf16 weight convert
__global__ __launch_bounds__(256) void cvt_w(const float* __restrict__ s0, const float* __restrict__ s1,
                                             const float* __restrict__ s2, const float* __restrict__ s3,
                                             u16* __restrict__ d){
  const float* srcs[4] = {s0, s1, s2, s3};
  const float* s = srcs[blockIdx.y];
  u16* dd = d + (size_t)blockIdx.y * (1024u * 1024u);
  const int i = (blockIdx.x * 256 + threadIdx.x) * 4;
  float4 v = *(const float4*)(s + i);
  uint2 o;
  o.x = (u32)f2b(v.x) | ((u32)f2b(v.y) << 16);
  o.y = (u32)f2b(v.z) | ((u32)f2b(v.w) << 16);
  *(uint2*)(dd + i) = o;
}

// ---------------------------------------------------------------- LayerNorm (fp32 in, bf16 out)
__global__ __launch_bounds__(256) void ln_kernel(const float* __restrict__ x, const float* __restrict__ g,
                                                 const float* __restrict__ be, u16* __restrict__ h){
  const int row = blockIdx.x, tid = threadIdx.x;
  const float* xr = x + (size_t)row * 1024u;
  float4 raw = *(const float4*)(xr + tid * 4);
  float s  = raw.x + raw.y + raw.z + raw.w;
  float sq = raw.x*raw.x + raw.y*raw.y + raw.z*raw.z + raw.w*raw.w;
  #pragma unroll
  for (int m = 1; m < 64; m <<= 1){ s += __shfl_xor(s, m); sq += __shfl_xor(sq, m); }
  __shared__ float ws[4], wq[4];
  if ((tid & 63) == 0){ ws[tid >> 6] = s; wq[tid >> 6] = sq; }
  __syncthreads();
  s  = ws[0] + ws[1] + ws[2] + ws[3];
  sq = wq[0] + wq[1] + wq[2] + wq[3];
  const float mu = s * (1.0f / 1024.0f);
  const float rstd = rsqrtf(sq * (1.0f / 1024.0f) - mu * mu + 1e-5f);
  float4 gg = *(const float4*)(g + tid * 4);
  float4 bb = *(const float4*)(be + tid * 4);
  float y0 = (raw.x - mu) * rstd * gg.x + bb.x;
  float y1 = (raw.y - mu) * rstd * gg.y + bb.y;
  float y2 = (raw.z - mu) * rstd * gg.z + bb.z;
  float y3 = (raw.w - mu) * rstd * gg.w + bb.w;
  uint2 outv;
  outv.x = (u32)f2b(y0) | ((u32)f2b(y1) << 16);
  outv.y = (u32)f2b(y2) | ((u32)f2b(y3) << 16);
  *(uint2*)(h + (size_t)row * 1024u + tid * 4) = outv;
}

// ---------------------------------------------------------------- fused QKV GEMM: [q|k|v] = h * Wcat^T + b
// r13: global_load_lds staging (m151: ~35% cheaper than reg-staging at 128^2)
// + double-buffered LDS + counted vmcnt(4) + RAW s_barrier (no compiler
// vmcnt(0) drain). Schedule per kt:
//   gll tile(kt+1)->buf^1 ; vmcnt(4) ; s_barrier ; ds_read+MFMA(buf cur) ;
//   lgkmcnt(0)+sched_barrier ; s_barrier
// Race audit: buf^1 last read at kt-1, whose tail lgkm+barrier guarantees read
// data returned before any wave's gll writes. Keeps r11 XOR swizzle and the
// LDS-staged 64B-line Vt epilogue. MFMA order unchanged -> bit-identical.
__global__ __launch_bounds__(256) void gemm_qkv(const u16* __restrict__ A, const u16* __restrict__ Wcat,
                                                const float* __restrict__ bq, const float* __restrict__ bk,
                                                const float* __restrict__ bv,
                                                u16* __restrict__ qo, u16* __restrict__ ko, u16* __restrict__ vt){
  __shared__ u16 lA[2][4096];
  __shared__ u16 lB[2][4096];
  const int tid = threadIdx.x;
  const int lane = tid & 63, wv = tid >> 6, l15 = lane & 15, quad = lane >> 4;
  const int wr = wv >> 1, wc = wv & 1;
  const int row0 = blockIdx.x * 128, col0 = blockIdx.y * 128;
  const int K = 1024;

  const int r0_ = tid >> 2,         c0_ = tid & 3;
  const int r1_ = (256 + tid) >> 2, c1_ = (256 + tid) & 3;
  const u16* Asrc0 = A    + (size_t)(row0 + r0_) * K + (c0_ ^ ((r0_ >> 1) & 3)) * 8;
  const u16* Asrc1 = A    + (size_t)(row0 + r1_) * K + (c1_ ^ ((r1_ >> 1) & 3)) * 8;
  const u16* Bsrc0 = Wcat + (size_t)(col0 + r0_) * K + (c0_ ^ ((r0_ >> 1) & 3)) * 8;
  const u16* Bsrc1 = Wcat + (size_t)(col0 + r1_) * K + (c1_ ^ ((r1_ >> 1) & 3)) * 8;
  const int cr = (quad ^ ((l15 >> 1) & 3)) * 8;

  f32x4 acc[4][4] = {};

  // prologue: tile0 -> buf0
  GLL(Asrc0, &lA[0][tid * 8]);
  GLL(Asrc1, &lA[0][(256 + tid) * 8]);
  GLL(Bsrc0, &lB[0][tid * 8]);
  GLL(Bsrc1, &lB[0][(256 + tid) * 8]);

  for (int kt = 0; kt < 32; ++kt){
    const int cur = kt & 1;
    if (kt < 31){
      const int o = (kt + 1) * 32;
      GLL(Asrc0 + o, &lA[cur ^ 1][tid * 8]);
      GLL(Asrc1 + o, &lA[cur ^ 1][(256 + tid) * 8]);
      GLL(Bsrc0 + o, &lB[cur ^ 1][tid * 8]);
      GLL(Bsrc1 + o, &lB[cur ^ 1][(256 + tid) * 8]);
      asm volatile("s_waitcnt vmcnt(4)" ::: "memory");
    } else {
      asm volatile("s_waitcnt vmcnt(0)" ::: "memory");
    }
    asm volatile("s_barrier" ::: "memory");
    bf16x8 af[4], bf[4];
    #pragma unroll
    for (int i = 0; i < 4; ++i) af[i] = *(const bf16x8*)&lA[cur][(wr * 64 + i * 16 + l15) * 32 + cr];
    #pragma unroll
    for (int j = 0; j < 4; ++j) bf[j] = *(const bf16x8*)&lB[cur][(wc * 64 + j * 16 + l15) * 32 + cr];
    #pragma unroll
    for (int i = 0; i < 4; ++i)
      #pragma unroll
      for (int j = 0; j < 4; ++j)
        acc[i][j] = __builtin_amdgcn_mfma_f32_16x16x32_bf16(af[i], bf[j], acc[i][j], 0, 0, 0);
    asm volatile("s_waitcnt lgkmcnt(0)" ::: "memory");
    __builtin_amdgcn_sched_barrier(0);
    asm volatile("s_barrier" ::: "memory");
  }

  const int sel = col0 >> 10;
  if (sel < 2){
    const float* bias = (sel == 0) ? bq : bk;
    u16* dst = (sel == 0) ? qo : ko;
    #pragma unroll
    for (int i = 0; i < 4; ++i){
      const int grow = row0 + wr * 64 + i * 16 + quad * 4;
      #pragma unroll
      for (int j = 0; j < 4; ++j){
        const int gcol = (col0 & 1023) + wc * 64 + j * 16 + l15;
        const float bb = bias[gcol];
        #pragma unroll
        for (int r = 0; r < 4; ++r){
          size_t off = (size_t)(grow + r) * 1024u + gcol;
          dst[off] = f2b(acc[i][j][r] + bb);
        }
      }
    }
  } else {
    // V: transpose through wave-private LDS, write Vt[(b*16+head)*64+d][s]
    // as one full 64B line per d-row per pass.
    u16* pw = &lA[0][0] + wv * 2048;          // [64 d][32 s] u16, 8B-unit XOR u^=d&7
    const int bglob = row0 >> 11;
    const int head  = ((col0 & 1023) >> 6) + wc;
    const int srem0 = (row0 & 2047) + wr * 64;
    const size_t vbase = (size_t)((bglob * 16 + head) * 64) * 2048u;
    #pragma unroll
    for (int p = 0; p < 2; ++p){
      #pragma unroll
      for (int i2 = 0; i2 < 2; ++i2){
        const int i = p * 2 + i2;
        #pragma unroll
        for (int j = 0; j < 4; ++j){
          const int d = j * 16 + l15;
          const float bv_ = bv[(col0 & 1023) + wc * 64 + d];
          const int u = (i2 * 4 + quad) ^ (d & 7);
          uint2 pk;
          pk.x = (u32)f2b(acc[i][j][0] + bv_) | ((u32)f2b(acc[i][j][1] + bv_) << 16);
          pk.y = (u32)f2b(acc[i][j][2] + bv_) | ((u32)f2b(acc[i][j][3] + bv_) << 16);
          *(uint2*)&pw[d * 32 + u * 4] = pk;
        }
      }
      // wave-internal in-order LDS: reads below see the writes above
      const int dl = lane;
      #pragma unroll
      for (int c = 0; c < 4; ++c){
        const int u0 = (2 * c) ^ (dl & 7), u1 = (2 * c + 1) ^ (dl & 7);
        uint2 lo = *(const uint2*)&pw[dl * 32 + u0 * 4];
        uint2 hi = *(const uint2*)&pw[dl * 32 + u1 * 4];
        uint4 o4; o4.x = lo.x; o4.y = lo.y; o4.z = hi.x; o4.w = hi.y;
        *(uint4*)(vt + vbase + (size_t)dl * 2048u + srem0 + p * 32 + c * 8) = o4;
      }
    }
  }
}

// ---------------------------------------------------------------- GEMM: C = A * W^T + bias + res, fp32 out
// r13: same gll + dbuf + counted-vmcnt + raw-barrier structure as gemm_qkv.
__global__ __launch_bounds__(256) void gemm_out(const u16* __restrict__ A, const u16* __restrict__ W,
                                                const float* __restrict__ bias, const float* __restrict__ res,
                                                float* __restrict__ C, int M, int N, int K){
  __shared__ u16 lA[2][4096];
  __shared__ u16 lB[2][4096];
  const int tid = threadIdx.x;
  const int lane = tid & 63, wv = tid >> 6, l15 = lane & 15, quad = lane >> 4;
  const int wr = wv >> 1, wc = wv & 1;
  const int row0 = blockIdx.x * 128, col0 = blockIdx.y * 128;

  const int r0_ = tid >> 2,         c0_ = tid & 3;
  const int r1_ = (256 + tid) >> 2, c1_ = (256 + tid) & 3;
  const u16* Asrc0 = A + (size_t)(row0 + r0_) * K + (c0_ ^ ((r0_ >> 1) & 3)) * 8;
  const u16* Asrc1 = A + (size_t)(row0 + r1_) * K + (c1_ ^ ((r1_ >> 1) & 3)) * 8;
  const u16* Bsrc0 = W + (size_t)(col0 + r0_) * K + (c0_ ^ ((r0_ >> 1) & 3)) * 8;
  const u16* Bsrc1 = W + (size_t)(col0 + r1_) * K + (c1_ ^ ((r1_ >> 1) & 3)) * 8;
  const int cr = (quad ^ ((l15 >> 1) & 3)) * 8;

  f32x4 acc[4][4] = {};
  const int nkt = K >> 5;

  GLL(Asrc0, &lA[0][tid * 8]);
  GLL(Asrc1, &lA[0][(256 + tid) * 8]);
  GLL(Bsrc0, &lB[0][tid * 8]);
  GLL(Bsrc1, &lB[0][(256 + tid) * 8]);

  for (int kt = 0; kt < nkt; ++kt){
    const int cur = kt & 1;
    if (kt < nkt - 1){
      const int o = (kt + 1) * 32;
      GLL(Asrc0 + o, &lA[cur ^ 1][tid * 8]);
      GLL(Asrc1 + o, &lA[cur ^ 1][(256 + tid) * 8]);
      GLL(Bsrc0 + o, &lB[cur ^ 1][tid * 8]);
      GLL(Bsrc1 + o, &lB[cur ^ 1][(256 + tid) * 8]);
      asm volatile("s_waitcnt vmcnt(4)" ::: "memory");
    } else {
      asm volatile("s_waitcnt vmcnt(0)" ::: "memory");
    }
    asm volatile("s_barrier" ::: "memory");
    bf16x8 af[4], bf[4];
    #pragma unroll
    for (int i = 0; i < 4; ++i) af[i] = *(const bf16x8*)&lA[cur][(wr * 64 + i * 16 + l15) * 32 + cr];
    #pragma unroll
    for (int j = 0; j < 4; ++j) bf[j] = *(const bf16x8*)&lB[cur][(wc * 64 + j * 16 + l15) * 32 + cr];
    #pragma unroll
    for (int i = 0; i < 4; ++i)
      #pragma unroll
      for (int j = 0; j < 4; ++j)
        acc[i][j] = __builtin_amdgcn_mfma_f32_16x16x32_bf16(af[i], bf[j], acc[i][j], 0, 0, 0);
    asm volatile("s_waitcnt lgkmcnt(0)" ::: "memory");
    __builtin_amdgcn_sched_barrier(0);
    asm volatile("s_barrier" ::: "memory");
  }
  #pragma unroll
  for (int i = 0; i < 4; ++i){
    const int grow = row0 + wr * 64 + i * 16 + quad * 4;
    #pragma unroll
    for (int j = 0; j < 4; ++j){
      const int gcol = col0 + wc * 64 + j * 16 + l15;
      const float bb = bias[gcol];
      #pragma unroll
      for (int r = 0; r < 4; ++r){
        size_t off = (size_t)(grow + r) * N + gcol;
        C[off] = acc[i][j][r] + bb + res[off];
      }
    }
  }
}

// ---------------------------------------------------------------- flash attention (bf16 in/out)
// r10 structure (verified): 64 q-rows/wave (4 q-groups), grid 512, 2 blocks/CU;
// permlane butterfly P-redistribution, K/V dbuf single-barrier loop, both-sides
// XOR swizzle (0 conflicts), ones-MFMA denominator.
__global__ __launch_bounds__(256, 2) void attn_kernel(const u16* __restrict__ Q, const u16* __restrict__ K,
                                                      const u16* __restrict__ Vt, u16* __restrict__ O){
  __shared__ u16 kls[2][64 * 64];
  __shared__ u16 vls[2][64 * 64];
  const int tid = threadIdx.x;
  const int lane = tid & 63, wv = tid >> 6, l15 = lane & 15, quad = lane >> 4;
  const int bh = blockIdx.x & 63, qt = blockIdx.x >> 6;
  const int b = bh >> 4, hh = bh & 15;
  const int q0 = qt * 256;
  const u16* Qg = Q + ((size_t)b * 2048u) * 1024u + hh * 64;
  const u16* Kg = K + ((size_t)b * 2048u) * 1024u + hh * 64;
  const u16* Vg = Vt + (size_t)bh * 64u * 2048u;
  u16* Og = O + ((size_t)b * 2048u) * 1024u + hh * 64;

  const int sr = tid >> 3, sc = tid & 7, sr2 = sr + 32;
  const int sx = (sc ^ (sr & 7)) * 8;
  const int c0 = ((quad ^ (l15 & 7))) * 8;

  const float QSCALE = 0.125f * 1.44269504f;
  bf16x8 qf2[4][2];
  #pragma unroll
  for (int g = 0; g < 4; ++g)
    #pragma unroll
    for (int kk = 0; kk < 2; ++kk){
      qf2[g][kk] = *(const bf16x8*)(Qg + (size_t)(q0 + wv * 64 + g * 16 + l15) * 1024u + kk * 32 + quad * 8);
      #pragma unroll
      for (int e = 0; e < 8; ++e) qf2[g][kk][e] = (__bf16)((float)qf2[g][kk][e] * QSCALE);
    }

  bf16x8 ones_f;
  {
    const __bf16 onev = (__bf16)1.0f, zerov = (__bf16)0.0f;
    #pragma unroll
    for (int e = 0; e < 8; ++e) ones_f[e] = (l15 == 0) ? onev : zerov;
  }

  f32x4 o2[4][4] = {};
  f32x4 o_l[4] = {};
  const f32x4 zf = {0.f, 0.f, 0.f, 0.f};

  uint4 kr0, kr1, vr0, vr1;
  kr0 = *(const uint4*)(Kg + (size_t)sr  * 1024u + sc * 8);
  vr0 = *(const uint4*)(Vg + (size_t)sr  * 2048u + sc * 8);
  kr1 = *(const uint4*)(Kg + (size_t)sr2 * 1024u + sc * 8);
  vr1 = *(const uint4*)(Vg + (size_t)sr2 * 2048u + sc * 8);
  *(uint4*)&kls[0][sr  * 64 + sx] = kr0;
  *(uint4*)&vls[0][sr  * 64 + sx] = vr0;
  *(uint4*)&kls[0][sr2 * 64 + sx] = kr1;
  *(uint4*)&vls[0][sr2 * 64 + sx] = vr1;
  kr0 = *(const uint4*)(Kg + (size_t)(64 + sr)  * 1024u + sc * 8);
  vr0 = *(const uint4*)(Vg + (size_t)sr  * 2048u + 64 + sc * 8);
  kr1 = *(const uint4*)(Kg + (size_t)(64 + sr2) * 1024u + sc * 8);
  vr1 = *(const uint4*)(Vg + (size_t)sr2 * 2048u + 64 + sc * 8);
  __syncthreads();

  for (int kt = 0; kt < 32; ++kt){
    const int cur = kt & 1;
    const u16* kb = kls[cur];
    const u16* vb = vls[cur];
    if (kt < 31){
      u16* kw = kls[cur ^ 1];
      u16* vw = vls[cur ^ 1];
      *(uint4*)&kw[sr  * 64 + sx] = kr0;
      *(uint4*)&vw[sr  * 64 + sx] = vr0;
      *(uint4*)&kw[sr2 * 64 + sx] = kr1;
      *(uint4*)&vw[sr2 * 64 + sx] = vr1;
    }
    if (kt < 30){
      const int s0 = (kt + 2) * 64;
      kr0 = *(const uint4*)(Kg + (size_t)(s0 + sr)  * 1024u + sc * 8);
      vr0 = *(const uint4*)(Vg + (size_t)sr  * 2048u + s0 + sc * 8);
      kr1 = *(const uint4*)(Kg + (size_t)(s0 + sr2) * 1024u + sc * 8);
      vr1 = *(const uint4*)(Vg + (size_t)sr2 * 2048u + s0 + sc * 8);
    }

    f32x4 s2[4][4];
    #pragma unroll
    for (int j = 0; j < 4; ++j){
      const int rb = (j * 16 + l15) * 64;
      bf16x8 kfr0 = *(const bf16x8*)&kb[rb + c0];
      bf16x8 kfr1 = *(const bf16x8*)&kb[rb + (c0 ^ 32)];
      #pragma unroll
      for (int g = 0; g < 4; ++g){
        f32x4 a = __builtin_amdgcn_mfma_f32_16x16x32_bf16(kfr0, qf2[g][0], zf, 0, 0, 0);
        s2[g][j] = __builtin_amdgcn_mfma_f32_16x16x32_bf16(kfr1, qf2[g][1], a, 0, 0, 0);
      }
    }

    #pragma unroll
    for (int g = 0; g < 4; ++g)
      #pragma unroll
      for (int j = 0; j < 4; ++j)
        #pragma unroll
        for (int r = 0; r < 4; ++r)
          s2[g][j][r] = __builtin_amdgcn_exp2f(s2[g][j][r]);

    #pragma unroll
    for (int kk = 0; kk < 2; ++kk){
      bf16x8 afr[4];
      #pragma unroll
      for (int g = 0; g < 4; ++g){
        const int j0 = kk * 2, j1 = j0 + 1;
        u32 A0 = pk_bf16_trunc(s2[g][j0][0], s2[g][j0][1]);
        u32 A1 = pk_bf16_trunc(s2[g][j0][2], s2[g][j0][3]);
        u32 B0 = pk_bf16_trunc(s2[g][j1][0], s2[g][j1][1]);
        u32 B1 = pk_bf16_trunc(s2[g][j1][2], s2[g][j1][3]);
        u32x2 r1 = __builtin_amdgcn_permlane32_swap(A0, B0, false, false);
        u32x2 r2 = __builtin_amdgcn_permlane16_swap(r1[0], r1[1], false, false);
        u32x2 r3 = __builtin_amdgcn_permlane32_swap(A1, B1, false, false);
        u32x2 r4 = __builtin_amdgcn_permlane16_swap(r3[0], r3[1], false, false);
        union { uint4 u; bf16x8 v; } cv;
        cv.u.x = r2[0]; cv.u.y = r4[0]; cv.u.z = r2[1]; cv.u.w = r4[1];
        afr[g] = cv.v;
      }
      #pragma unroll
      for (int g = 0; g < 4; ++g)
        o_l[g] = __builtin_amdgcn_mfma_f32_16x16x32_bf16(afr[g], ones_f, o_l[g], 0, 0, 0);
      #pragma unroll
      for (int j2 = 0; j2 < 4; ++j2){
        bf16x8 bfr = *(const bf16x8*)&vb[(j2 * 16 + l15) * 64 + (c0 ^ (kk * 32))];
        #pragma unroll
        for (int g = 0; g < 4; ++g)
          o2[g][j2] = __builtin_amdgcn_mfma_f32_16x16x32_bf16(afr[g], bfr, o2[g][j2], 0, 0, 0);
      }
    }
    __syncthreads();
  }

  #pragma unroll
  for (int g = 0; g < 4; ++g){
    float lr[4];
    #pragma unroll
    for (int r = 0; r < 4; ++r) lr[r] = 1.0f / __shfl(o_l[g][r], quad * 16);
    #pragma unroll
    for (int j2 = 0; j2 < 4; ++j2){
      #pragma unroll
      for (int r = 0; r < 4; ++r){
        const int qrow = q0 + wv * 64 + g * 16 + quad * 4 + r;
        const int d = j2 * 16 + l15;
        Og[(size_t)qrow * 1024u + d] = f2b(o2[g][j2][r] * lr[r]);
      }
    }
  }
}

extern "C" void kernel_launch(void* const* d_in, const int* in_sizes, int n_in,
                              void* d_out, int out_size, void* d_ws, size_t ws_size,
                              hipStream_t stream){
  (void)in_sizes; (void)n_in; (void)out_size; (void)ws_size;
  const float* x   = (const float*)d_in[0];
  const float* Wq  = (const float*)d_in[1];
  const float* bq  = (const float*)d_in[2];
  const float* Wk  = (const float*)d_in[3];
  const float* bk  = (const float*)d_in[4];
  const float* Wv  = (const float*)d_in[5];
  const float* bv  = (const float*)d_in[6];
  const float* Wo  = (const float*)d_in[7];
  const float* bo  = (const float*)d_in[8];
  const float* lng = (const float*)d_in[9];
  const float* lnb = (const float*)d_in[10];
  float* out = (float*)d_out;

  const size_t TE = (size_t)8192 * 1024;
  u16* ws0 = (u16*)d_ws;          // h
  u16* ws1 = ws0 + TE;            // q -> attention out (in place)
  u16* ws2 = ws1 + TE;            // k
  u16* wsw = ws2 + TE;            // bf16 weights: Wq|Wk|Wv|Wo contiguous
  u16* wob = wsw + (size_t)3 * 1024 * 1024;
  u16* vt  = (u16*)d_out;         // Vt (b,h,d,s) bf16 scratch inside d_out

  cvt_w<<<dim3(1024, 4), 256, 0, stream>>>(Wq, Wk, Wv, Wo, wsw);
  ln_kernel<<<dim3(8192), 256, 0, stream>>>(x, lng, lnb, ws0);
  gemm_qkv<<<dim3(64, 24), 256, 0, stream>>>(ws0, wsw, bq, bk, bv, ws1, ws2, vt);
  attn_kernel<<<dim3(512), 256, 0, stream>>>(ws1, ws2, vt, ws1);
  gemm_out<<<dim3(64, 8), 256, 0, stream>>>(ws1, wob, bo, x, out, 8192, 1024, 1024);
}

// Round 7
// 266.188 us; speedup vs baseline: 1.0923x; 1.0923x over previous
//
#include <hip/hip_runtime.h>

typedef unsigned short u16;
typedef unsigned int   u32;
using bf16x8 = __attribute__((ext_vector_type(8))) __bf16;
using f32x4  = __attribute__((ext_vector_type(4))) float;
using u32x2  = __attribute__((ext_vector_type(2))) unsigned int;

__device__ __forceinline__ u16 f2b(float f){
  union { float f; u32 i; } v; v.f = f;
  u32 r = v.i + 0x7FFFu + ((v.i >> 16) & 1u);
  return (u16)(r >> 16);
}
__device__ __forceinline__ u32 pk_bf16_trunc(float a, float b){
  return __builtin_amdgcn_perm(__float_as_uint(b), __float_as_uint(a), 0x07060302u);
}

// ---------------------------------------------------------------- fp32 -> bf16 weight convert
__global__ __launch_bounds__(256) void cvt_w(const float* __restrict__ s0, const float* __restrict__ s1,
                                             const float* __restrict__ s2, const float* __restrict__ s3,
                                             u16* __restrict__ d){
  const float* srcs[4] = {s0, s1, s2, s3};
  const float* s = srcs[blockIdx.y];
  u16* dd = d + (size_t)blockIdx.y * (1024u * 1024u);
  const int i = (blockIdx.x * 256 + threadIdx.x) * 4;
  float4 v = *(const float4*)(s + i);
  uint2 o;
  o.x = (u32)f2b(v.x) | ((u32)f2b(v.y) << 16);
  o.y = (u32)f2b(v.z) | ((u32)f2b(v.w) << 16);
  *(uint2*)(dd + i) = o;
}

// ---------------------------------------------------------------- LayerNorm (fp32 in, bf16 out)
__global__ __launch_bounds__(256) void ln_kernel(const float* __restrict__ x, const float* __restrict__ g,
                                                 const float* __restrict__ be, u16* __restrict__ h){
  const int row = blockIdx.x, tid = threadIdx.x;
  const float* xr = x + (size_t)row * 1024u;
  float4 raw = *(const float4*)(xr + tid * 4);
  float s  = raw.x + raw.y + raw.z + raw.w;
  float sq = raw.x*raw.x + raw.y*raw.y + raw.z*raw.z + raw.w*raw.w;
  #pragma unroll
  for (int m = 1; m < 64; m <<= 1){ s += __shfl_xor(s, m); sq += __shfl_xor(sq, m); }
  __shared__ float ws[4], wq[4];
  if ((tid & 63) == 0){ ws[tid >> 6] = s; wq[tid >> 6] = sq; }
  __syncthreads();
  s  = ws[0] + ws[1] + ws[2] + ws[3];
  sq = wq[0] + wq[1] + wq[2] + wq[3];
  const float mu = s * (1.0f / 1024.0f);
  const float rstd = rsqrtf(sq * (1.0f / 1024.0f) - mu * mu + 1e-5f);
  float4 gg = *(const float4*)(g + tid * 4);
  float4 bb = *(const float4*)(be + tid * 4);
  float y0 = (raw.x - mu) * rstd * gg.x + bb.x;
  float y1 = (raw.y - mu) * rstd * gg.y + bb.y;
  float y2 = (raw.z - mu) * rstd * gg.z + bb.z;
  float y3 = (raw.w - mu) * rstd * gg.w + bb.w;
  uint2 outv;
  outv.x = (u32)f2b(y0) | ((u32)f2b(y1) << 16);
  outv.y = (u32)f2b(y2) | ((u32)f2b(y3) << 16);
  *(uint2*)(h + (size_t)row * 1024u + tid * 4) = outv;
}

// ---------------------------------------------------------------- fused QKV GEMM: [q|k|v] = h * Wcat^T + b
// r14 = r12 verbatim (best measured GEMM variant this session; the r13
// counted-vmcnt rewrite regressed: 1-deep gll prefetch < load latency at BK=32,
// plus sched_barrier(0) order-pinning). Reg-staged prefetch 2 K-tiles ahead,
// dbuf LDS, ONE __syncthreads per kt; r11 XOR swizzle; LDS-staged Vt epilogue.
__global__ __launch_bounds__(256) void gemm_qkv(const u16* __restrict__ A, const u16* __restrict__ Wcat,
                                                const float* __restrict__ bq, const float* __restrict__ bk,
                                                const float* __restrict__ bv,
                                                u16* __restrict__ qo, u16* __restrict__ ko, u16* __restrict__ vt){
  __shared__ u16 lA[2][4096];
  __shared__ u16 lB[2][4096];
  const int tid = threadIdx.x;
  const int lane = tid & 63, wv = tid >> 6, l15 = lane & 15, quad = lane >> 4;
  const int wr = wv >> 1, wc = wv & 1;
  const int row0 = blockIdx.x * 128, col0 = blockIdx.y * 128;
  const int K = 1024;

  const int r0_ = tid >> 2,         c0_ = tid & 3;
  const int r1_ = (256 + tid) >> 2, c1_ = (256 + tid) & 3;
  const u16* Asrc0 = A    + (size_t)(row0 + r0_) * K + (c0_ ^ ((r0_ >> 1) & 3)) * 8;
  const u16* Asrc1 = A    + (size_t)(row0 + r1_) * K + (c1_ ^ ((r1_ >> 1) & 3)) * 8;
  const u16* Bsrc0 = Wcat + (size_t)(col0 + r0_) * K + (c0_ ^ ((r0_ >> 1) & 3)) * 8;
  const u16* Bsrc1 = Wcat + (size_t)(col0 + r1_) * K + (c1_ ^ ((r1_ >> 1) & 3)) * 8;
  const int cr = (quad ^ ((l15 >> 1) & 3)) * 8;

  f32x4 acc[4][4] = {};
  uint4 ar0, ar1, br0, br1;
  // prologue: tile0 -> LDS buf0 (via regs), tile1 -> regs
  ar0 = *(const uint4*)(Asrc0);
  ar1 = *(const uint4*)(Asrc1);
  br0 = *(const uint4*)(Bsrc0);
  br1 = *(const uint4*)(Bsrc1);
  *(uint4*)&lA[0][tid * 8] = ar0;
  *(uint4*)&lA[0][(256 + tid) * 8] = ar1;
  *(uint4*)&lB[0][tid * 8] = br0;
  *(uint4*)&lB[0][(256 + tid) * 8] = br1;
  ar0 = *(const uint4*)(Asrc0 + 32);
  ar1 = *(const uint4*)(Asrc1 + 32);
  br0 = *(const uint4*)(Bsrc0 + 32);
  br1 = *(const uint4*)(Bsrc1 + 32);
  __syncthreads();

  for (int kt = 0; kt < 32; ++kt){
    const int cur = kt & 1;
    if (kt < 31){
      *(uint4*)&lA[cur ^ 1][tid * 8] = ar0;
      *(uint4*)&lA[cur ^ 1][(256 + tid) * 8] = ar1;
      *(uint4*)&lB[cur ^ 1][tid * 8] = br0;
      *(uint4*)&lB[cur ^ 1][(256 + tid) * 8] = br1;
    }
    if (kt < 30){
      const int o = (kt + 2) * 32;
      ar0 = *(const uint4*)(Asrc0 + o);
      ar1 = *(const uint4*)(Asrc1 + o);
      br0 = *(const uint4*)(Bsrc0 + o);
      br1 = *(const uint4*)(Bsrc1 + o);
    }
    bf16x8 af[4], bf[4];
    #pragma unroll
    for (int i = 0; i < 4; ++i) af[i] = *(const bf16x8*)&lA[cur][(wr * 64 + i * 16 + l15) * 32 + cr];
    #pragma unroll
    for (int j = 0; j < 4; ++j) bf[j] = *(const bf16x8*)&lB[cur][(wc * 64 + j * 16 + l15) * 32 + cr];
    #pragma unroll
    for (int i = 0; i < 4; ++i)
      #pragma unroll
      for (int j = 0; j < 4; ++j)
        acc[i][j] = __builtin_amdgcn_mfma_f32_16x16x32_bf16(af[i], bf[j], acc[i][j], 0, 0, 0);
    __syncthreads();
  }
  const int sel = col0 >> 10;
  if (sel < 2){
    const float* bias = (sel == 0) ? bq : bk;
    u16* dst = (sel == 0) ? qo : ko;
    #pragma unroll
    for (int i = 0; i < 4; ++i){
      const int grow = row0 + wr * 64 + i * 16 + quad * 4;
      #pragma unroll
      for (int j = 0; j < 4; ++j){
        const int gcol = (col0 & 1023) + wc * 64 + j * 16 + l15;
        const float bb = bias[gcol];
        #pragma unroll
        for (int r = 0; r < 4; ++r){
          size_t off = (size_t)(grow + r) * 1024u + gcol;
          dst[off] = f2b(acc[i][j][r] + bb);
        }
      }
    }
  } else {
    // V: transpose through wave-private LDS, write Vt[(b*16+head)*64+d][s]
    // as one full 64B line per d-row per pass.
    u16* pw = &lA[0][0] + wv * 2048;          // [64 d][32 s] u16, 8B-unit XOR u^=d&7
    const int bglob = row0 >> 11;
    const int head  = ((col0 & 1023) >> 6) + wc;
    const int srem0 = (row0 & 2047) + wr * 64;
    const size_t vbase = (size_t)((bglob * 16 + head) * 64) * 2048u;
    #pragma unroll
    for (int p = 0; p < 2; ++p){
      #pragma unroll
      for (int i2 = 0; i2 < 2; ++i2){
        const int i = p * 2 + i2;
        #pragma unroll
        for (int j = 0; j < 4; ++j){
          const int d = j * 16 + l15;
          const float bv_ = bv[(col0 & 1023) + wc * 64 + d];
          const int u = (i2 * 4 + quad) ^ (d & 7);
          uint2 pk;
          pk.x = (u32)f2b(acc[i][j][0] + bv_) | ((u32)f2b(acc[i][j][1] + bv_) << 16);
          pk.y = (u32)f2b(acc[i][j][2] + bv_) | ((u32)f2b(acc[i][j][3] + bv_) << 16);
          *(uint2*)&pw[d * 32 + u * 4] = pk;
        }
      }
      // wave-internal in-order LDS: reads below see the writes above
      const int dl = lane;
      #pragma unroll
      for (int c = 0; c < 4; ++c){
        const int u0 = (2 * c) ^ (dl & 7), u1 = (2 * c + 1) ^ (dl & 7);
        uint2 lo = *(const uint2*)&pw[dl * 32 + u0 * 4];
        uint2 hi = *(const uint2*)&pw[dl * 32 + u1 * 4];
        uint4 o4; o4.x = lo.x; o4.y = lo.y; o4.z = hi.x; o4.w = hi.y;
        *(uint4*)(vt + vbase + (size_t)dl * 2048u + srem0 + p * 32 + c * 8) = o4;
      }
    }
  }
}

// ---------------------------------------------------------------- GEMM: C = A * W^T + bias + res, fp32 out
// r14 = r12 verbatim.
__global__ __launch_bounds__(256) void gemm_out(const u16* __restrict__ A, const u16* __restrict__ W,
                                                const float* __restrict__ bias, const float* __restrict__ res,
                                                float* __restrict__ C, int M, int N, int K){
  __shared__ u16 lA[2][4096];
  __shared__ u16 lB[2][4096];
  const int tid = threadIdx.x;
  const int lane = tid & 63, wv = tid >> 6, l15 = lane & 15, quad = lane >> 4;
  const int wr = wv >> 1, wc = wv & 1;
  const int row0 = blockIdx.x * 128, col0 = blockIdx.y * 128;

  const int r0_ = tid >> 2,         c0_ = tid & 3;
  const int r1_ = (256 + tid) >> 2, c1_ = (256 + tid) & 3;
  const u16* Asrc0 = A + (size_t)(row0 + r0_) * K + (c0_ ^ ((r0_ >> 1) & 3)) * 8;
  const u16* Asrc1 = A + (size_t)(row0 + r1_) * K + (c1_ ^ ((r1_ >> 1) & 3)) * 8;
  const u16* Bsrc0 = W + (size_t)(col0 + r0_) * K + (c0_ ^ ((r0_ >> 1) & 3)) * 8;
  const u16* Bsrc1 = W + (size_t)(col0 + r1_) * K + (c1_ ^ ((r1_ >> 1) & 3)) * 8;
  const int cr = (quad ^ ((l15 >> 1) & 3)) * 8;

  f32x4 acc[4][4] = {};
  const int nkt = K >> 5;
  uint4 ar0, ar1, br0, br1;
  ar0 = *(const uint4*)(Asrc0);
  ar1 = *(const uint4*)(Asrc1);
  br0 = *(const uint4*)(Bsrc0);
  br1 = *(const uint4*)(Bsrc1);
  *(uint4*)&lA[0][tid * 8] = ar0;
  *(uint4*)&lA[0][(256 + tid) * 8] = ar1;
  *(uint4*)&lB[0][tid * 8] = br0;
  *(uint4*)&lB[0][(256 + tid) * 8] = br1;
  ar0 = *(const uint4*)(Asrc0 + 32);
  ar1 = *(const uint4*)(Asrc1 + 32);
  br0 = *(const uint4*)(Bsrc0 + 32);
  br1 = *(const uint4*)(Bsrc1 + 32);
  __syncthreads();

  for (int kt = 0; kt < nkt; ++kt){
    const int cur = kt & 1;
    if (kt < nkt - 1){
      *(uint4*)&lA[cur ^ 1][tid * 8] = ar0;
      *(uint4*)&lA[cur ^ 1][(256 + tid) * 8] = ar1;
      *(uint4*)&lB[cur ^ 1][tid * 8] = br0;
      *(uint4*)&lB[cur ^ 1][(256 + tid) * 8] = br1;
    }
    if (kt < nkt - 2){
      const int o = (kt + 2) * 32;
      ar0 = *(const uint4*)(Asrc0 + o);
      ar1 = *(const uint4*)(Asrc1 + o);
      br0 = *(const uint4*)(Bsrc0 + o);
      br1 = *(const uint4*)(Bsrc1 + o);
    }
    bf16x8 af[4], bf[4];
    #pragma unroll
    for (int i = 0; i < 4; ++i) af[i] = *(const bf16x8*)&lA[cur][(wr * 64 + i * 16 + l15) * 32 + cr];
    #pragma unroll
    for (int j = 0; j < 4; ++j) bf[j] = *(const bf16x8*)&lB[cur][(wc * 64 + j * 16 + l15) * 32 + cr];
    #pragma unroll
    for (int i = 0; i < 4; ++i)
      #pragma unroll
      for (int j = 0; j < 4; ++j)
        acc[i][j] = __builtin_amdgcn_mfma_f32_16x16x32_bf16(af[i], bf[j], acc[i][j], 0, 0, 0);
    __syncthreads();
  }
  #pragma unroll
  for (int i = 0; i < 4; ++i){
    const int grow = row0 + wr * 64 + i * 16 + quad * 4;
    #pragma unroll
    for (int j = 0; j < 4; ++j){
      const int gcol = col0 + wc * 64 + j * 16 + l15;
      const float bb = bias[gcol];
      #pragma unroll
      for (int r = 0; r < 4; ++r){
        size_t off = (size_t)(grow + r) * N + gcol;
        C[off] = acc[i][j][r] + bb + res[off];
      }
    }
  }
}

// ---------------------------------------------------------------- flash attention (bf16 in/out)
// r14: r10 structure + T5 s_setprio(1) around the MFMA clusters (QK j-loop and
// the per-kk PV cluster). Mechanism: 2 independent blocks/CU, 8 waves at
// different phases -> CU scheduler can favor MFMA-issuing waves (m191: +4-7%
// on attn; null only on barrier-lockstep GEMMs).
__global__ __launch_bounds__(256, 2) void attn_kernel(const u16* __restrict__ Q, const u16* __restrict__ K,
                                                      const u16* __restrict__ Vt, u16* __restrict__ O){
  __shared__ u16 kls[2][64 * 64];
  __shared__ u16 vls[2][64 * 64];
  const int tid = threadIdx.x;
  const int lane = tid & 63, wv = tid >> 6, l15 = lane & 15, quad = lane >> 4;
  const int bh = blockIdx.x & 63, qt = blockIdx.x >> 6;
  const int b = bh >> 4, hh = bh & 15;
  const int q0 = qt * 256;
  const u16* Qg = Q + ((size_t)b * 2048u) * 1024u + hh * 64;
  const u16* Kg = K + ((size_t)b * 2048u) * 1024u + hh * 64;
  const u16* Vg = Vt + (size_t)bh * 64u * 2048u;
  u16* Og = O + ((size_t)b * 2048u) * 1024u + hh * 64;

  const int sr = tid >> 3, sc = tid & 7, sr2 = sr + 32;
  const int sx = (sc ^ (sr & 7)) * 8;
  const int c0 = ((quad ^ (l15 & 7))) * 8;

  const float QSCALE = 0.125f * 1.44269504f;
  bf16x8 qf2[4][2];
  #pragma unroll
  for (int g = 0; g < 4; ++g)
    #pragma unroll
    for (int kk = 0; kk < 2; ++kk){
      qf2[g][kk] = *(const bf16x8*)(Qg + (size_t)(q0 + wv * 64 + g * 16 + l15) * 1024u + kk * 32 + quad * 8);
      #pragma unroll
      for (int e = 0; e < 8; ++e) qf2[g][kk][e] = (__bf16)((float)qf2[g][kk][e] * QSCALE);
    }

  bf16x8 ones_f;
  {
    const __bf16 onev = (__bf16)1.0f, zerov = (__bf16)0.0f;
    #pragma unroll
    for (int e = 0; e < 8; ++e) ones_f[e] = (l15 == 0) ? onev : zerov;
  }

  f32x4 o2[4][4] = {};
  f32x4 o_l[4] = {};
  const f32x4 zf = {0.f, 0.f, 0.f, 0.f};

  uint4 kr0, kr1, vr0, vr1;
  kr0 = *(const uint4*)(Kg + (size_t)sr  * 1024u + sc * 8);
  vr0 = *(const uint4*)(Vg + (size_t)sr  * 2048u + sc * 8);
  kr1 = *(const uint4*)(Kg + (size_t)sr2 * 1024u + sc * 8);
  vr1 = *(const uint4*)(Vg + (size_t)sr2 * 2048u + sc * 8);
  *(uint4*)&kls[0][sr  * 64 + sx] = kr0;
  *(uint4*)&vls[0][sr  * 64 + sx] = vr0;
  *(uint4*)&kls[0][sr2 * 64 + sx] = kr1;
  *(uint4*)&vls[0][sr2 * 64 + sx] = vr1;
  kr0 = *(const uint4*)(Kg + (size_t)(64 + sr)  * 1024u + sc * 8);
  vr0 = *(const uint4*)(Vg + (size_t)sr  * 2048u + 64 + sc * 8);
  kr1 = *(const uint4*)(Kg + (size_t)(64 + sr2) * 1024u + sc * 8);
  vr1 = *(const uint4*)(Vg + (size_t)sr2 * 2048u + 64 + sc * 8);
  __syncthreads();

  for (int kt = 0; kt < 32; ++kt){
    const int cur = kt & 1;
    const u16* kb = kls[cur];
    const u16* vb = vls[cur];
    if (kt < 31){
      u16* kw = kls[cur ^ 1];
      u16* vw = vls[cur ^ 1];
      *(uint4*)&kw[sr  * 64 + sx] = kr0;
      *(uint4*)&vw[sr  * 64 + sx] = vr0;
      *(uint4*)&kw[sr2 * 64 + sx] = kr1;
      *(uint4*)&vw[sr2 * 64 + sx] = vr1;
    }
    if (kt < 30){
      const int s0 = (kt + 2) * 64;
      kr0 = *(const uint4*)(Kg + (size_t)(s0 + sr)  * 1024u + sc * 8);
      vr0 = *(const uint4*)(Vg + (size_t)sr  * 2048u + s0 + sc * 8);
      kr1 = *(const uint4*)(Kg + (size_t)(s0 + sr2) * 1024u + sc * 8);
      vr1 = *(const uint4*)(Vg + (size_t)sr2 * 2048u + s0 + sc * 8);
    }

    f32x4 s2[4][4];
    __builtin_amdgcn_s_setprio(1);
    #pragma unroll
    for (int j = 0; j < 4; ++j){
      const int rb = (j * 16 + l15) * 64;
      bf16x8 kfr0 = *(const bf16x8*)&kb[rb + c0];
      bf16x8 kfr1 = *(const bf16x8*)&kb[rb + (c0 ^ 32)];
      #pragma unroll
      for (int g = 0; g < 4; ++g){
        f32x4 a = __builtin_amdgcn_mfma_f32_16x16x32_bf16(kfr0, qf2[g][0], zf, 0, 0, 0);
        s2[g][j] = __builtin_amdgcn_mfma_f32_16x16x32_bf16(kfr1, qf2[g][1], a, 0, 0, 0);
      }
    }
    __builtin_amdgcn_s_setprio(0);

    #pragma unroll
    for (int g = 0; g < 4; ++g)
      #pragma unroll
      for (int j = 0; j < 4; ++j)
        #pragma unroll
        for (int r = 0; r < 4; ++r)
          s2[g][j][r] = __builtin_amdgcn_exp2f(s2[g][j][r]);

    #pragma unroll
    for (int kk = 0; kk < 2; ++kk){
      bf16x8 afr[4];
      #pragma unroll
      for (int g = 0; g < 4; ++g){
        const int j0 = kk * 2, j1 = j0 + 1;
        u32 A0 = pk_bf16_trunc(s2[g][j0][0], s2[g][j0][1]);
        u32 A1 = pk_bf16_trunc(s2[g][j0][2], s2[g][j0][3]);
        u32 B0 = pk_bf16_trunc(s2[g][j1][0], s2[g][j1][1]);
        u32 B1 = pk_bf16_trunc(s2[g][j1][2], s2[g][j1][3]);
        u32x2 r1 = __builtin_amdgcn_permlane32_swap(A0, B0, false, false);
        u32x2 r2 = __builtin_amdgcn_permlane16_swap(r1[0], r1[1], false, false);
        u32x2 r3 = __builtin_amdgcn_permlane32_swap(A1, B1, false, false);
        u32x2 r4 = __builtin_amdgcn_permlane16_swap(r3[0], r3[1], false, false);
        union { uint4 u; bf16x8 v; } cv;
        cv.u.x = r2[0]; cv.u.y = r4[0]; cv.u.z = r2[1]; cv.u.w = r4[1];
        afr[g] = cv.v;
      }
      __builtin_amdgcn_s_setprio(1);
      #pragma unroll
      for (int g = 0; g < 4; ++g)
        o_l[g] = __builtin_amdgcn_mfma_f32_16x16x32_bf16(afr[g], ones_f, o_l[g], 0, 0, 0);
      #pragma unroll
      for (int j2 = 0; j2 < 4; ++j2){
        bf16x8 bfr = *(const bf16x8*)&vb[(j2 * 16 + l15) * 64 + (c0 ^ (kk * 32))];
        #pragma unroll
        for (int g = 0; g < 4; ++g)
          o2[g][j2] = __builtin_amdgcn_mfma_f32_16x16x32_bf16(afr[g], bfr, o2[g][j2], 0, 0, 0);
      }
      __builtin_amdgcn_s_setprio(0);
    }
    __syncthreads();
  }

  #pragma unroll
  for (int g = 0; g < 4; ++g){
    float lr[4];
    #pragma unroll
    for (int r = 0; r < 4; ++r) lr[r] = 1.0f / __shfl(o_l[g][r], quad * 16);
    #pragma unroll
    for (int j2 = 0; j2 < 4; ++j2){
      #pragma unroll
      for (int r = 0; r < 4; ++r){
        const int qrow = q0 + wv * 64 + g * 16 + quad * 4 + r;
        const int d = j2 * 16 + l15;
        Og[(size_t)qrow * 1024u + d] = f2b(o2[g][j2][r] * lr[r]);
      }
    }
  }
}

extern "C" void kernel_launch(void* const* d_in, const int* in_sizes, int n_in,
                              void* d_out, int out_size, void* d_ws, size_t ws_size,
                              hipStream_t stream){
  (void)in_sizes; (void)n_in; (void)out_size; (void)ws_size;
  const float* x   = (const float*)d_in[0];
  const float* Wq  = (const float*)d_in[1];
  const float* bq  = (const float*)d_in[2];
  const float* Wk  = (const float*)d_in[3];
  const float* bk  = (const float*)d_in[4];
  const float* Wv  = (const float*)d_in[5];
  const float* bv  = (const float*)d_in[6];
  const float* Wo  = (const float*)d_in[7];
  const float* bo  = (const float*)d_in[8];
  const float* lng = (const float*)d_in[9];
  const float* lnb = (const float*)d_in[10];
  float* out = (float*)d_out;

  const size_t TE = (size_t)8192 * 1024;
  u16* ws0 = (u16*)d_ws;          // h
  u16* ws1 = ws0 + TE;            // q -> attention out (in place)
  u16* ws2 = ws1 + TE;            // k
  u16* wsw = ws2 + TE;            // bf16 weights: Wq|Wk|Wv|Wo contiguous
  u16* wob = wsw + (size_t)3 * 1024 * 1024;
  u16* vt  = (u16*)d_out;         // Vt (b,h,d,s) bf16 scratch inside d_out

  cvt_w<<<dim3(1024, 4), 256, 0, stream>>>(Wq, Wk, Wv, Wo, wsw);
  ln_kernel<<<dim3(8192), 256, 0, stream>>>(x, lng, lnb, ws0);
  gemm_qkv<<<dim3(64, 24), 256, 0, stream>>>(ws0, wsw, bq, bk, bv, ws1, ws2, vt);
  attn_kernel<<<dim3(512), 256, 0, stream>>>(ws1, ws2, vt, ws1);
  gemm_out<<<dim3(64, 8), 256, 0, stream>>>(ws1, wob, bo, x, out, 8192, 1024, 1024);
}